// Round 1
// baseline (5639.749 us; speedup 1.0000x reference)
//
#include <hip/hip_runtime.h>
#include <math.h>

#define ND    8388608   // N*D
#define NTOK  8192
#define DIM   1024
#define NEXP  8
#define CAP   1024
#define TSEQ  2048

// ---------------- init ----------------
__global__ void k_init_small(const float* __restrict__ phase, const int* __restrict__ Lptr,
                             float* __restrict__ rc, float* __restrict__ rs,
                             int* __restrict__ ctl) {
    int d = blockIdx.x * blockDim.x + threadIdx.x;
    if (d < DIM) { rc[d] = cosf(phase[d]); rs[d] = sinf(phase[d]); }
    if (d == 0) {
        ctl[0] = 0;                       // done flag
        ctl[1] = 0;                       // iters_run
        int L = Lptr[0];
        int mi = L - 1; if (mi < 1) mi = 1;
        ctl[2] = mi;                      // max_iters
    }
}

__global__ void k_init_big(const float* __restrict__ xr, const float* __restrict__ xi,
                           float* __restrict__ zre, float* __restrict__ zim,
                           float* __restrict__ tre, float* __restrict__ tim,
                           const float* __restrict__ rc, const float* __restrict__ rs) {
    int i = blockIdx.x * blockDim.x + threadIdx.x;
    if (i >= ND) return;
    float xre = xr[i], xim_ = xi[i];
    zre[i] = xre; zim[i] = xim_;
    int d = i & (DIM - 1);
    int g = i >> 10;              // token index (b*T + t)
    int t = g & (TSEQ - 1);
    float trv, tiv;
    if (t == 0) { trv = xre; tiv = xim_; }
    else {
        float ar = xr[i - DIM], ai = xi[i - DIM];
        float c = rc[d], s = rs[d];
        trv = ar * c - ai * s;
        tiv = ar * s + ai * c;
    }
    tre[i] = trv; tim[i] = tiv;
}

// ---------------- gating: logits + softmax ----------------
// one wave per token; lane covers d = lane, lane+64, ...
__global__ __launch_bounds__(256) void k_gate_softmax(
    const float* __restrict__ zre, const float* __restrict__ Wg, const float* __restrict__ bg,
    float* __restrict__ S, float* __restrict__ sumbuf,
    const int* __restrict__ ctl, int iter) {
    if (iter >= 0 && (ctl[0] || iter >= ctl[2])) return;
    if (blockIdx.x == 0 && threadIdx.x == 0) *sumbuf = 0.0f;
    int wave = threadIdx.x >> 6;
    int lane = threadIdx.x & 63;
    int n = blockIdx.x * 4 + wave;        // 2048 blocks * 4 waves = 8192 tokens
    float acc[NEXP] = {0,0,0,0,0,0,0,0};
    const float* zr = zre + (size_t)n * DIM;
    for (int d = lane; d < DIM; d += 64) {
        float zv = zr[d];
        const float4 w0 = *(const float4*)(Wg + d * 8);
        const float4 w1 = *(const float4*)(Wg + d * 8 + 4);
        acc[0] += zv * w0.x; acc[1] += zv * w0.y; acc[2] += zv * w0.z; acc[3] += zv * w0.w;
        acc[4] += zv * w1.x; acc[5] += zv * w1.y; acc[6] += zv * w1.z; acc[7] += zv * w1.w;
    }
    #pragma unroll
    for (int off = 32; off > 0; off >>= 1)
        #pragma unroll
        for (int e = 0; e < NEXP; ++e) acc[e] += __shfl_xor(acc[e], off);
    if (lane == 0) {
        float m = -1e30f;
        #pragma unroll
        for (int e = 0; e < NEXP; ++e) { acc[e] += bg[e]; m = fmaxf(m, acc[e]); }
        float ssum = 0.0f;
        #pragma unroll
        for (int e = 0; e < NEXP; ++e) { acc[e] = expf(acc[e] - m); ssum += acc[e]; }
        float inv = 1.0f / ssum;
        #pragma unroll
        for (int e = 0; e < NEXP; ++e) S[n * 8 + e] = acc[e] * inv;
    }
}

// ---------------- top-k per expert: full bitonic sort in LDS ----------------
// key = (score_bits << 32) | ~token  -> ascending sort, take last CAP.
// ties in score: lower token => bigger key => selected (matches jax top_k).
__global__ __launch_bounds__(1024) void k_topk(
    const float* __restrict__ S, int* __restrict__ idxs, float* __restrict__ scs,
    const int* __restrict__ ctl, int iter) {
    if (iter >= 0 && (ctl[0] || iter >= ctl[2])) return;
    __shared__ unsigned long long keys[NTOK];   // 64 KiB
    int e = blockIdx.x;
    int tid = threadIdx.x;
    for (int n = tid; n < NTOK; n += 1024) {
        unsigned int vb = __float_as_uint(S[n * 8 + e]);   // softmax > 0: bits are order-preserving
        keys[n] = ((unsigned long long)vb << 32) | (unsigned int)(0xFFFFFFFFu - (unsigned int)n);
    }
    __syncthreads();
    for (int k = 2; k <= NTOK; k <<= 1) {
        for (int j = k >> 1; j > 0; j >>= 1) {
            for (int i = tid; i < NTOK; i += 1024) {
                int ixj = i ^ j;
                if (ixj > i) {
                    unsigned long long a = keys[i], b = keys[ixj];
                    bool up = ((i & k) == 0);
                    if ((a > b) == up) { keys[i] = b; keys[ixj] = a; }
                }
            }
            __syncthreads();
        }
    }
    if (tid < CAP) {
        unsigned long long kv = keys[NTOK - CAP + tid];
        int n = (int)(0xFFFFFFFFu - (unsigned int)(kv & 0xFFFFFFFFu));
        idxs[e * CAP + tid] = n;
        scs[e * CAP + tid]  = __uint_as_float((unsigned int)(kv >> 32));
    }
}

// ---------------- expert GEMM + scatter ----------------
// per expert e: out[k][h] = sum_d z[idx[e][k]][d] * We[e][d][h]  (re & im share B tile)
// y[idx] += score * (out + be)   (be -> real part only)
#define BM 64
#define BN 64
#define BKK 16
__global__ __launch_bounds__(256) void k_moe_gemm_scatter(
    const float* __restrict__ zre, const float* __restrict__ zim,
    const float* __restrict__ We, const float* __restrict__ be,
    const int* __restrict__ idxs, const float* __restrict__ scs,
    float* __restrict__ pre, float* __restrict__ pim,
    const int* __restrict__ ctl, int iter) {
    if (iter >= 0 && (ctl[0] || iter >= ctl[2])) return;
    int e = blockIdx.z, bx = blockIdx.x, by = blockIdx.y;
    __shared__ float Bs[BKK][BN];
    __shared__ float Ar[BM][BKK + 1];
    __shared__ float Ai[BM][BKK + 1];
    __shared__ int   tokL[BM];
    __shared__ float scL[BM];
    int tid = threadIdx.x;
    if (tid < BM) {
        int g = e * CAP + by * BM + tid;
        tokL[tid] = idxs[g];
        scL[tid]  = scs[g];
    }
    __syncthreads();
    int tx = tid & 15, ty = tid >> 4;
    float accr[4][4] = {{0}}; float acci[4][4] = {{0}};
    const float* Wb = We + (size_t)e * DIM * DIM + bx * BN;
    int arow = tid >> 2;             // 0..63
    int acol = (tid & 3) * 4;        // 0,4,8,12
    size_t abase = (size_t)tokL[arow] * DIM + acol;
    int brow = tid >> 4;             // 0..15
    int bcol = (tid & 15) * 4;       // 0..60
    for (int kt = 0; kt < DIM; kt += BKK) {
        float4 bv = *(const float4*)(Wb + (size_t)(kt + brow) * DIM + bcol);
        Bs[brow][bcol] = bv.x; Bs[brow][bcol + 1] = bv.y;
        Bs[brow][bcol + 2] = bv.z; Bs[brow][bcol + 3] = bv.w;
        float4 vr = *(const float4*)(zre + abase + kt);
        float4 vi = *(const float4*)(zim + abase + kt);
        Ar[arow][acol] = vr.x; Ar[arow][acol + 1] = vr.y;
        Ar[arow][acol + 2] = vr.z; Ar[arow][acol + 3] = vr.w;
        Ai[arow][acol] = vi.x; Ai[arow][acol + 1] = vi.y;
        Ai[arow][acol + 2] = vi.z; Ai[arow][acol + 3] = vi.w;
        __syncthreads();
        #pragma unroll
        for (int kk = 0; kk < BKK; ++kk) {
            float b[4], ar[4], ai[4];
            #pragma unroll
            for (int j = 0; j < 4; ++j) b[j] = Bs[kk][tx * 4 + j];
            #pragma unroll
            for (int i = 0; i < 4; ++i) { ar[i] = Ar[ty * 4 + i][kk]; ai[i] = Ai[ty * 4 + i][kk]; }
            #pragma unroll
            for (int i = 0; i < 4; ++i)
                #pragma unroll
                for (int j = 0; j < 4; ++j) {
                    accr[i][j] += ar[i] * b[j];
                    acci[i][j] += ai[i] * b[j];
                }
        }
        __syncthreads();
    }
    int c0 = bx * BN + tx * 4;
    #pragma unroll
    for (int i = 0; i < 4; ++i) {
        int rr = ty * 4 + i;
        int tok = tokL[rr];
        float s = scL[rr];
        size_t ob = (size_t)tok * DIM + c0;
        #pragma unroll
        for (int j = 0; j < 4; ++j) {
            atomicAdd(&pre[ob + j], s * (accr[i][j] + be[e * DIM + c0 + j]));
            atomicAdd(&pim[ob + j], s * acci[i][j]);
        }
    }
}

// ---------------- residual, z update, |r| reduction ----------------
__global__ __launch_bounds__(256) void k_resid_update(
    float* __restrict__ zre, float* __restrict__ zim,
    const float* __restrict__ tre, const float* __restrict__ tim,
    const float* __restrict__ pre, const float* __restrict__ pim,
    float lr, float* __restrict__ sumbuf, const int* __restrict__ ctl, int iter) {
    if (ctl[0] || iter >= ctl[2]) return;
    __shared__ float red[256];
    float local = 0.0f;
    int stride = gridDim.x * blockDim.x;
    for (int i = blockIdx.x * blockDim.x + threadIdx.x; i < ND; i += stride) {
        float rr = tre[i] - pre[i];
        float ri = tim[i] - pim[i];
        zre[i] += lr * rr;
        zim[i] += lr * ri;
        local += sqrtf(rr * rr + ri * ri);
    }
    red[threadIdx.x] = local;
    __syncthreads();
    for (int s = 128; s > 0; s >>= 1) {
        if (threadIdx.x < s) red[threadIdx.x] += red[threadIdx.x + s];
        __syncthreads();
    }
    if (threadIdx.x == 0) atomicAdd(sumbuf, red[0]);
}

__global__ void k_finalize(const float* __restrict__ sumbuf, int* __restrict__ ctl, int iter) {
    if (ctl[0] || iter >= ctl[2]) return;
    ctl[1] = iter + 1;
    float mean = *sumbuf * (1.0f / (float)ND);
    if (mean < 0.001f) ctl[0] = 1;
}

// ---------------- final: z += 0.5*(tgt - pred); write stacked output ----------------
__global__ void k_final_zupd(float* __restrict__ zre, float* __restrict__ zim,
                             const float* __restrict__ tre, const float* __restrict__ tim,
                             const float* __restrict__ pre, const float* __restrict__ pim) {
    int i = blockIdx.x * blockDim.x + threadIdx.x;
    if (i >= ND) return;
    zre[i] += 0.5f * (tre[i] - pre[i]);
    zim[i] += 0.5f * (tim[i] - pim[i]);
}

__global__ void k_write_out(const float* __restrict__ zre, const float* __restrict__ zim,
                            float* __restrict__ out, const int* __restrict__ ctl) {
    int i = blockIdx.x * blockDim.x + threadIdx.x;
    if (i >= ND) return;
    out[2 * i]     = zre[i];
    out[2 * i + 1] = zim[i];
    if (i == 0) out[(size_t)2 * ND] = (float)ctl[1];
}

// ---------------- host ----------------
extern "C" void kernel_launch(void* const* d_in, const int* in_sizes, int n_in,
                              void* d_out, int out_size, void* d_ws, size_t ws_size,
                              hipStream_t stream) {
    (void)in_sizes; (void)n_in; (void)out_size; (void)ws_size;
    const float* x_real = (const float*)d_in[0];
    const float* x_imag = (const float*)d_in[1];
    const float* phase  = (const float*)d_in[2];
    const float* Wg     = (const float*)d_in[3];
    const float* bg     = (const float*)d_in[4];
    const float* We     = (const float*)d_in[5];
    const float* be     = (const float*)d_in[6];
    const int*   Lptr   = (const int*)d_in[7];

    float* ws  = (float*)d_ws;
    float* zre = ws;
    float* zim = ws + (size_t)ND;
    float* tre = ws + (size_t)2 * ND;
    float* tim = ws + (size_t)3 * ND;
    float* S   = ws + (size_t)4 * ND;          // 8192*8
    float* scs = S + NTOK * NEXP;              // 8*1024
    int*   idxs = (int*)(scs + NEXP * CAP);    // 8*1024
    float* rc  = (float*)(idxs + NEXP * CAP);  // 1024
    float* rs  = rc + DIM;                     // 1024
    float* sumbuf = rs + DIM;                  // 1
    int*   ctl = (int*)(sumbuf + 1);           // 3 ints

    float* pre = (float*)d_out;                // pred.real scratch
    float* pim = pre + (size_t)ND;             // pred.imag scratch

    k_init_small<<<4, 256, 0, stream>>>(phase, Lptr, rc, rs, ctl);
    k_init_big<<<ND / 256, 256, 0, stream>>>(x_real, x_imag, zre, zim, tre, tim, rc, rs);

    dim3 ggrid(DIM / BN, CAP / BM, NEXP);
    float lr = 0.5f;
    for (int it = 0; it < 7; ++it) {
        k_gate_softmax<<<NTOK / 4, 256, 0, stream>>>(zre, Wg, bg, S, sumbuf, ctl, it);
        k_topk<<<NEXP, 1024, 0, stream>>>(S, idxs, scs, ctl, it);
        hipMemsetAsync(d_out, 0, (size_t)2 * ND * sizeof(float), stream);
        k_moe_gemm_scatter<<<ggrid, 256, 0, stream>>>(zre, zim, We, be, idxs, scs, pre, pim, ctl, it);
        k_resid_update<<<2048, 256, 0, stream>>>(zre, zim, tre, tim, pre, pim, lr, sumbuf, ctl, it);
        k_finalize<<<1, 1, 0, stream>>>(sumbuf, ctl, it);
        lr *= 0.85f;
    }

    // final (ungated) MoE on z_final, then out = z + 0.5*(tgt - pred)
    k_gate_softmax<<<NTOK / 4, 256, 0, stream>>>(zre, Wg, bg, S, sumbuf, ctl, -1);
    k_topk<<<NEXP, 1024, 0, stream>>>(S, idxs, scs, ctl, -1);
    hipMemsetAsync(d_out, 0, (size_t)2 * ND * sizeof(float), stream);
    k_moe_gemm_scatter<<<ggrid, 256, 0, stream>>>(zre, zim, We, be, idxs, scs, pre, pim, ctl, -1);
    k_final_zupd<<<ND / 256, 256, 0, stream>>>(zre, zim, tre, tim, pre, pim);
    k_write_out<<<ND / 256, 256, 0, stream>>>(zre, zim, (float*)d_out, ctl);
}

// Round 2
// 2667.924 us; speedup vs baseline: 2.1139x; 2.1139x over previous
//
#include <hip/hip_runtime.h>
#include <math.h>

#define ND    8388608
#define NTOK  8192
#define DIM   1024
#define NEXP  8
#define CAP   1024
#define TSEQ  2048

typedef short bf16x8 __attribute__((ext_vector_type(8)));
typedef unsigned short u16x8 __attribute__((ext_vector_type(8)));
typedef float f32x4 __attribute__((ext_vector_type(4)));

#define AS1 __attribute__((address_space(1)))
#define AS3 __attribute__((address_space(3)))

__device__ __forceinline__ void gload_lds16(const void* g, void* l) {
    __builtin_amdgcn_global_load_lds((const AS1 unsigned int*)g,
                                     (AS3 unsigned int*)l, 16, 0, 0);
}

__device__ __forceinline__ unsigned short f2bf(float x) {
    union { float f; unsigned u; } v; v.f = x;
    unsigned r = v.u + 0x7FFFu + ((v.u >> 16) & 1u);
    return (unsigned short)(r >> 16);
}
__device__ __forceinline__ float bf2f(unsigned short b) {
    union { unsigned u; float f; } v; v.u = ((unsigned)b) << 16; return v.f;
}

// ---------------- init ----------------
__global__ void k_init_small(const float* __restrict__ phase, const int* __restrict__ Lptr,
                             float* __restrict__ rc, float* __restrict__ rs,
                             int* __restrict__ ctl) {
    int d = blockIdx.x * blockDim.x + threadIdx.x;
    if (d < DIM) { rc[d] = cosf(phase[d]); rs[d] = sinf(phase[d]); }
    if (d == 0) {
        ctl[0] = 0; ctl[1] = 0;
        int L = Lptr[0]; int mi = L - 1; if (mi < 1) mi = 1;
        ctl[2] = mi;
    }
}

__global__ void k_init_big(const float* __restrict__ xr, const float* __restrict__ xi,
                           float* __restrict__ zre, unsigned short* __restrict__ zimB) {
    int i = blockIdx.x * blockDim.x + threadIdx.x;
    if (i >= ND) return;
    zre[i] = xr[i];
    zimB[i] = f2bf(xi[i]);
}

// ---------------- one-time: We -> weT hi/lo bf16, [e][h][d], slot-swizzled by h&7 ----------------
__global__ __launch_bounds__(256) void k_wconv(const float* __restrict__ We,
                                               unsigned short* __restrict__ Whi,
                                               unsigned short* __restrict__ Wlo) {
    __shared__ float lds[64][65];
    int e = blockIdx.z, h0 = blockIdx.x * 64, d0 = blockIdx.y * 64;
    int tid = threadIdx.x;
    #pragma unroll
    for (int q = 0; q < 16; ++q) {
        int idx = q * 256 + tid;
        int i = idx >> 6, j = idx & 63;
        lds[i][j] = We[(size_t)e * 1048576 + (size_t)(d0 + i) * 1024 + h0 + j];
    }
    __syncthreads();
    #pragma unroll
    for (int q = 0; q < 2; ++q) {
        int sid = q * 256 + tid;
        int j = sid >> 3, sp = sid & 7;
        int h = h0 + j;
        int slog = sp ^ (h & 7);
        u16x8 hi, lo;
        #pragma unroll
        for (int u = 0; u < 8; ++u) {
            float x = lds[slog * 8 + u][j];
            unsigned short hb = f2bf(x);
            hi[u] = hb;
            lo[u] = f2bf(x - bf2f(hb));
        }
        size_t o = (((size_t)(e << 10) + h) << 10) + d0 + sp * 8;
        *(u16x8*)(Whi + o) = hi;
        *(u16x8*)(Wlo + o) = lo;
    }
}

// ---------------- gating: logits + softmax ----------------
__global__ __launch_bounds__(256) void k_gate_softmax(
    const float* __restrict__ zre, const float* __restrict__ Wg, const float* __restrict__ bg,
    float* __restrict__ S, float* __restrict__ sumbuf,
    const int* __restrict__ ctl, int iter) {
    if (iter >= 0 && (ctl[0] || iter >= ctl[2])) return;
    if (blockIdx.x == 0 && threadIdx.x == 0) *sumbuf = 0.0f;
    int wave = threadIdx.x >> 6;
    int lane = threadIdx.x & 63;
    int n = blockIdx.x * 4 + wave;
    float acc[NEXP] = {0,0,0,0,0,0,0,0};
    const float* zr = zre + (size_t)n * DIM;
    for (int d = lane; d < DIM; d += 64) {
        float zv = zr[d];
        const float4 w0 = *(const float4*)(Wg + d * 8);
        const float4 w1 = *(const float4*)(Wg + d * 8 + 4);
        acc[0] += zv * w0.x; acc[1] += zv * w0.y; acc[2] += zv * w0.z; acc[3] += zv * w0.w;
        acc[4] += zv * w1.x; acc[5] += zv * w1.y; acc[6] += zv * w1.z; acc[7] += zv * w1.w;
    }
    #pragma unroll
    for (int off = 32; off > 0; off >>= 1)
        #pragma unroll
        for (int e = 0; e < NEXP; ++e) acc[e] += __shfl_xor(acc[e], off);
    if (lane == 0) {
        float m = -1e30f;
        #pragma unroll
        for (int e = 0; e < NEXP; ++e) { acc[e] += bg[e]; m = fmaxf(m, acc[e]); }
        float ssum = 0.0f;
        #pragma unroll
        for (int e = 0; e < NEXP; ++e) { acc[e] = expf(acc[e] - m); ssum += acc[e]; }
        float inv = 1.0f / ssum;
        #pragma unroll
        for (int e = 0; e < NEXP; ++e) S[n * 8 + e] = acc[e] * inv;
    }
}

// ---------------- top-k per expert: bitonic sort ----------------
__global__ __launch_bounds__(1024) void k_topk(
    const float* __restrict__ S, int* __restrict__ idxs, float* __restrict__ scs,
    const int* __restrict__ ctl, int iter) {
    if (iter >= 0 && (ctl[0] || iter >= ctl[2])) return;
    __shared__ unsigned long long keys[NTOK];
    int e = blockIdx.x;
    int tid = threadIdx.x;
    for (int n = tid; n < NTOK; n += 1024) {
        unsigned int vb = __float_as_uint(S[n * 8 + e]);
        keys[n] = ((unsigned long long)vb << 32) | (unsigned int)(0xFFFFFFFFu - (unsigned int)n);
    }
    __syncthreads();
    for (int k = 2; k <= NTOK; k <<= 1) {
        for (int j = k >> 1; j > 0; j >>= 1) {
            for (int i = tid; i < NTOK; i += 1024) {
                int ixj = i ^ j;
                if (ixj > i) {
                    unsigned long long a = keys[i], b = keys[ixj];
                    bool up = ((i & k) == 0);
                    if ((a > b) == up) { keys[i] = b; keys[ixj] = a; }
                }
            }
            __syncthreads();
        }
    }
    if (tid < CAP) {
        unsigned long long kv = keys[NTOK - CAP + tid];
        int n = (int)(0xFFFFFFFFu - (unsigned int)(kv & 0xFFFFFFFFu));
        idxs[e * CAP + tid] = n;
        scs[e * CAP + tid]  = __uint_as_float((unsigned int)(kv >> 32));
    }
}

// ---------------- gather selected z.re rows -> Ahi/Alo bf16, slot-swizzled by row&7 ----------------
__global__ __launch_bounds__(256) void k_gather_convert(
    const float* __restrict__ zre, const int* __restrict__ idxs,
    unsigned short* __restrict__ Ahi, unsigned short* __restrict__ Alo,
    const int* __restrict__ ctl, int iter) {
    if (iter >= 0 && (ctl[0] || iter >= ctl[2])) return;
    int g = blockIdx.x * 256 + threadIdx.x;       // 0 .. 8192*128-1
    int r = g >> 7;
    int sl = g & 127;
    int c = sl >> 3, sp = sl & 7;
    int slog = sp ^ (r & 7);
    int n = idxs[r];
    const float* src = zre + ((size_t)n << 10) + c * 64 + slog * 8;
    u16x8 hi, lo;
    #pragma unroll
    for (int u = 0; u < 8; ++u) {
        float x = src[u];
        unsigned short hb = f2bf(x);
        hi[u] = hb;
        lo[u] = f2bf(x - bf2f(hb));
    }
    size_t o = ((size_t)r << 10) + c * 64 + sp * 8;
    *(u16x8*)(Ahi + o) = hi;
    *(u16x8*)(Alo + o) = lo;
}

// ---------------- real GEMM: 3-pass hi/lo MFMA + scatter ----------------
__global__ __launch_bounds__(256, 2) void k_gemm_re(
    const unsigned short* __restrict__ Ahi, const unsigned short* __restrict__ Alo,
    const unsigned short* __restrict__ Whi, const unsigned short* __restrict__ Wlo,
    const float* __restrict__ be, const int* __restrict__ idxs, const float* __restrict__ scs,
    float* __restrict__ pre, const int* __restrict__ ctl, int iter) {
    if (iter >= 0 && (ctl[0] || iter >= ctl[2])) return;
    __shared__ unsigned short smem[32768];   // 64KB: Ahi|Alo|Whi|Wlo tiles, [128][64] each
    const int e = blockIdx.z, bx = blockIdx.x, by = blockIdx.y;
    const int tid = threadIdx.x;
    const int wid = tid >> 6, lane = tid & 63;
    const int wm = wid >> 1, wn = wid & 1;

    const unsigned short* srcbase;
    int rowbase;
    if (wid == 0)      { srcbase = Ahi; rowbase = (e << 10) + by * 128; }
    else if (wid == 1) { srcbase = Alo; rowbase = (e << 10) + by * 128; }
    else if (wid == 2) { srcbase = Whi; rowbase = (e << 10) + bx * 128; }
    else               { srcbase = Wlo; rowbase = (e << 10) + bx * 128; }
    const unsigned short* gsrc = srcbase + (((size_t)(rowbase + (lane >> 3))) << 10) + ((lane & 7) << 3);
    unsigned short* ldst = smem + (wid << 13);

    f32x4 acc[4][4];
    #pragma unroll
    for (int a = 0; a < 4; ++a)
        #pragma unroll
        for (int b = 0; b < 4; ++b) acc[a][b] = (f32x4){0.f, 0.f, 0.f, 0.f};

    for (int kt = 0; kt < DIM; kt += 64) {
        __syncthreads();
        #pragma unroll
        for (int i = 0; i < 16; ++i)
            gload_lds16(gsrc + kt + ((size_t)i << 13), ldst + i * 512);
        __syncthreads();
        #pragma unroll
        for (int ks = 0; ks < 2; ++ks) {
            const int slog = (ks << 2) + (lane >> 4);
            const int swz = (slog ^ (lane & 7)) << 3;
            bf16x8 ah[4], al[4], bh[4], bl[4];
            #pragma unroll
            for (int mi = 0; mi < 4; ++mi) {
                int off = ((wm * 64 + mi * 16 + (lane & 15)) << 6) + swz;
                ah[mi] = *(const bf16x8*)&smem[off];
                al[mi] = *(const bf16x8*)&smem[8192 + off];
            }
            #pragma unroll
            for (int ni = 0; ni < 4; ++ni) {
                int off = ((wn * 64 + ni * 16 + (lane & 15)) << 6) + swz;
                bh[ni] = *(const bf16x8*)&smem[16384 + off];
                bl[ni] = *(const bf16x8*)&smem[24576 + off];
            }
            #pragma unroll
            for (int mi = 0; mi < 4; ++mi)
                #pragma unroll
                for (int ni = 0; ni < 4; ++ni) {
                    acc[mi][ni] = __builtin_amdgcn_mfma_f32_16x16x32_bf16(ah[mi], bh[ni], acc[mi][ni], 0, 0, 0);
                    acc[mi][ni] = __builtin_amdgcn_mfma_f32_16x16x32_bf16(ah[mi], bl[ni], acc[mi][ni], 0, 0, 0);
                    acc[mi][ni] = __builtin_amdgcn_mfma_f32_16x16x32_bf16(al[mi], bh[ni], acc[mi][ni], 0, 0, 0);
                }
        }
    }
    const int colbase = bx * 128 + wn * 64 + (lane & 15);
    float bev[4];
    #pragma unroll
    for (int ni = 0; ni < 4; ++ni) bev[ni] = be[(e << 10) + colbase + ni * 16];
    const int rowg = (e << 10) + by * 128 + wm * 64 + ((lane >> 4) << 2);
    #pragma unroll
    for (int mi = 0; mi < 4; ++mi) {
        #pragma unroll
        for (int rg = 0; rg < 4; ++rg) {
            int k = rowg + mi * 16 + rg;
            int tok = idxs[k];
            float s = scs[k];
            float* ob = pre + ((size_t)tok << 10);
            #pragma unroll
            for (int ni = 0; ni < 4; ++ni)
                atomicAdd(ob + colbase + ni * 16, s * (acc[mi][ni][rg] + bev[ni]));
        }
    }
}

// ---------------- imag GEMM: 1-pass bf16 MFMA + scatter ----------------
__global__ __launch_bounds__(256, 2) void k_gemm_im(
    const unsigned short* __restrict__ zimB, const unsigned short* __restrict__ Whi,
    const int* __restrict__ idxs, const float* __restrict__ scs,
    float* __restrict__ pim, const int* __restrict__ ctl, int iter) {
    if (iter >= 0 && (ctl[0] || iter >= ctl[2])) return;
    __shared__ unsigned short smem[16384];   // Aim[8192] | Bhi[8192]
    __shared__ int   tokL[128];
    __shared__ float scL[128];
    const int e = blockIdx.z, bx = blockIdx.x, by = blockIdx.y;
    const int tid = threadIdx.x;
    const int wid = tid >> 6, lane = tid & 63;
    const int wm = wid >> 1, wn = wid & 1;
    if (tid < 128) {
        tokL[tid] = idxs[(e << 10) + by * 128 + tid];
        scL[tid]  = scs[(e << 10) + by * 128 + tid];
    }
    __syncthreads();

    f32x4 acc[4][4];
    #pragma unroll
    for (int a = 0; a < 4; ++a)
        #pragma unroll
        for (int b = 0; b < 4; ++b) acc[a][b] = (f32x4){0.f, 0.f, 0.f, 0.f};

    const int rl = lane >> 3;          // 0..7
    const int ch = lane & 7;
    const int swzst = (ch ^ rl) << 3;  // source-folded swizzle for A staging
    const unsigned short* wsrc = Whi + (((size_t)((e << 10) + bx * 128 + rl)) << 10) + (ch << 3);

    for (int kt = 0; kt < DIM; kt += 64) {
        __syncthreads();
        if (wid < 2) {
            u16x8 tmp[8];
            #pragma unroll
            for (int q = 0; q < 8; ++q) {
                int r = (wid << 6) + (q << 3) + rl;
                int tok = tokL[r];
                tmp[q] = *(const u16x8*)(zimB + ((size_t)tok << 10) + kt + swzst);
            }
            #pragma unroll
            for (int q = 0; q < 8; ++q) {
                int r = (wid << 6) + (q << 3) + rl;
                *(u16x8*)&smem[(r << 6) + (ch << 3)] = tmp[q];
            }
        } else {
            #pragma unroll
            for (int q = 0; q < 8; ++q) {
                int i = ((wid - 2) << 3) + q;
                gload_lds16(wsrc + kt + ((size_t)i << 13), smem + 8192 + i * 512);
            }
        }
        __syncthreads();
        #pragma unroll
        for (int ks = 0; ks < 2; ++ks) {
            const int slog = (ks << 2) + (lane >> 4);
            const int swz = (slog ^ (lane & 7)) << 3;
            bf16x8 am[4], bh[4];
            #pragma unroll
            for (int mi = 0; mi < 4; ++mi) {
                int off = ((wm * 64 + mi * 16 + (lane & 15)) << 6) + swz;
                am[mi] = *(const bf16x8*)&smem[off];
            }
            #pragma unroll
            for (int ni = 0; ni < 4; ++ni) {
                int off = ((wn * 64 + ni * 16 + (lane & 15)) << 6) + swz;
                bh[ni] = *(const bf16x8*)&smem[8192 + off];
            }
            #pragma unroll
            for (int mi = 0; mi < 4; ++mi)
                #pragma unroll
                for (int ni = 0; ni < 4; ++ni)
                    acc[mi][ni] = __builtin_amdgcn_mfma_f32_16x16x32_bf16(am[mi], bh[ni], acc[mi][ni], 0, 0, 0);
        }
    }
    const int colbase = bx * 128 + wn * 64 + (lane & 15);
    #pragma unroll
    for (int mi = 0; mi < 4; ++mi) {
        #pragma unroll
        for (int rg = 0; rg < 4; ++rg) {
            int rloc = wm * 64 + mi * 16 + ((lane >> 4) << 2) + rg;
            int tok = tokL[rloc];
            float s = scL[rloc];
            float* ob = pim + ((size_t)tok << 10);
            #pragma unroll
            for (int ni = 0; ni < 4; ++ni)
                atomicAdd(ob + colbase + ni * 16, s * acc[mi][ni][rg]);
        }
    }
}

// ---------------- residual, z update, |r| reduction (target recomputed from x) ----------------
__global__ __launch_bounds__(256) void k_resid_update(
    float* __restrict__ zre, unsigned short* __restrict__ zimB,
    const float* __restrict__ xr, const float* __restrict__ xi,
    const float* __restrict__ rc, const float* __restrict__ rs,
    const float* __restrict__ pre, const float* __restrict__ pim,
    float lr, float* __restrict__ sumbuf, const int* __restrict__ ctl, int iter) {
    if (ctl[0] || iter >= ctl[2]) return;
    __shared__ float red[256];
    float local = 0.0f;
    int stride = gridDim.x * blockDim.x;
    for (int i = blockIdx.x * blockDim.x + threadIdx.x; i < ND; i += stride) {
        int d = i & (DIM - 1);
        int t = (i >> 10) & (TSEQ - 1);
        float trv, tiv;
        if (t == 0) { trv = xr[i]; tiv = xi[i]; }
        else {
            float ar = xr[i - DIM], ai = xi[i - DIM];
            float c = rc[d], s = rs[d];
            trv = ar * c - ai * s;
            tiv = ar * s + ai * c;
        }
        float rr = trv - pre[i];
        float ri = tiv - pim[i];
        zre[i] += lr * rr;
        zimB[i] = f2bf(bf2f(zimB[i]) + lr * ri);
        local += sqrtf(rr * rr + ri * ri);
    }
    red[threadIdx.x] = local;
    __syncthreads();
    for (int s = 128; s > 0; s >>= 1) {
        if (threadIdx.x < s) red[threadIdx.x] += red[threadIdx.x + s];
        __syncthreads();
    }
    if (threadIdx.x == 0) atomicAdd(sumbuf, red[0]);
}

__global__ void k_finalize(const float* __restrict__ sumbuf, int* __restrict__ ctl, int iter) {
    if (ctl[0] || iter >= ctl[2]) return;
    ctl[1] = iter + 1;
    float mean = *sumbuf * (1.0f / (float)ND);
    if (mean < 0.001f) ctl[0] = 1;
}

// ---------------- final: z += 0.5*(tgt - pred); write stacked output ----------------
__global__ void k_final_zupd(float* __restrict__ zre, unsigned short* __restrict__ zimB,
                             const float* __restrict__ xr, const float* __restrict__ xi,
                             const float* __restrict__ rc, const float* __restrict__ rs,
                             const float* __restrict__ pre, const float* __restrict__ pim) {
    int i = blockIdx.x * blockDim.x + threadIdx.x;
    if (i >= ND) return;
    int d = i & (DIM - 1);
    int t = (i >> 10) & (TSEQ - 1);
    float trv, tiv;
    if (t == 0) { trv = xr[i]; tiv = xi[i]; }
    else {
        float ar = xr[i - DIM], ai = xi[i - DIM];
        float c = rc[d], s = rs[d];
        trv = ar * c - ai * s;
        tiv = ar * s + ai * c;
    }
    zre[i] += 0.5f * (trv - pre[i]);
    zimB[i] = f2bf(bf2f(zimB[i]) + 0.5f * (tiv - pim[i]));
}

__global__ void k_write_out(const float* __restrict__ zre, const unsigned short* __restrict__ zimB,
                            float* __restrict__ out, const int* __restrict__ ctl) {
    int i = blockIdx.x * blockDim.x + threadIdx.x;
    if (i >= ND) return;
    out[2 * i]     = zre[i];
    out[2 * i + 1] = bf2f(zimB[i]);
    if (i == 0) out[(size_t)2 * ND] = (float)ctl[1];
}

// ---------------- host ----------------
extern "C" void kernel_launch(void* const* d_in, const int* in_sizes, int n_in,
                              void* d_out, int out_size, void* d_ws, size_t ws_size,
                              hipStream_t stream) {
    (void)in_sizes; (void)n_in; (void)out_size; (void)ws_size;
    const float* x_real = (const float*)d_in[0];
    const float* x_imag = (const float*)d_in[1];
    const float* phase  = (const float*)d_in[2];
    const float* Wg     = (const float*)d_in[3];
    const float* bg     = (const float*)d_in[4];
    const float* We     = (const float*)d_in[5];
    const float* be     = (const float*)d_in[6];
    const int*   Lptr   = (const int*)d_in[7];

    char* wsb = (char*)d_ws;
    float*          zre  = (float*)wsb;                                  // 32MB
    unsigned short* zimB = (unsigned short*)(wsb + 33554432);            // 16MB
    unsigned short* Ahi  = (unsigned short*)(wsb + 50331648);            // 16MB
    unsigned short* Alo  = (unsigned short*)(wsb + 67108864);            // 16MB
    unsigned short* Whi  = (unsigned short*)(wsb + 83886080);            // 16MB
    unsigned short* Wlo  = (unsigned short*)(wsb + 100663296);           // 16MB
    float* S      = (float*)(wsb + 117440512);
    float* scs    = (float*)(wsb + 117702656);
    int*   idxs   = (int*)  (wsb + 117735424);
    float* rc     = (float*)(wsb + 117768192);
    float* rs     = (float*)(wsb + 117772288);
    float* sumbuf = (float*)(wsb + 117776384);
    int*   ctl    = (int*)  (wsb + 117776388);

    float* pre = (float*)d_out;
    float* pim = pre + (size_t)ND;

    k_init_small<<<4, 256, 0, stream>>>(phase, Lptr, rc, rs, ctl);
    k_init_big<<<ND / 256, 256, 0, stream>>>(x_real, x_imag, zre, zimB);
    k_wconv<<<dim3(16, 16, 8), 256, 0, stream>>>(We, Whi, Wlo);

    dim3 ggrid(8, 8, 8);
    float lr = 0.5f;
    for (int it = 0; it < 7; ++it) {
        k_gate_softmax<<<NTOK / 4, 256, 0, stream>>>(zre, Wg, bg, S, sumbuf, ctl, it);
        k_topk<<<NEXP, 1024, 0, stream>>>(S, idxs, scs, ctl, it);
        k_gather_convert<<<4096, 256, 0, stream>>>(zre, idxs, Ahi, Alo, ctl, it);
        hipMemsetAsync(d_out, 0, (size_t)2 * ND * sizeof(float), stream);
        k_gemm_re<<<ggrid, 256, 0, stream>>>(Ahi, Alo, Whi, Wlo, be, idxs, scs, pre, ctl, it);
        k_gemm_im<<<ggrid, 256, 0, stream>>>(zimB, Whi, idxs, scs, pim, ctl, it);
        k_resid_update<<<2048, 256, 0, stream>>>(zre, zimB, x_real, x_imag, rc, rs, pre, pim, lr, sumbuf, ctl, it);
        k_finalize<<<1, 1, 0, stream>>>(sumbuf, ctl, it);
        lr *= 0.85f;
    }

    k_gate_softmax<<<NTOK / 4, 256, 0, stream>>>(zre, Wg, bg, S, sumbuf, ctl, -1);
    k_topk<<<NEXP, 1024, 0, stream>>>(S, idxs, scs, ctl, -1);
    k_gather_convert<<<4096, 256, 0, stream>>>(zre, idxs, Ahi, Alo, ctl, -1);
    hipMemsetAsync(d_out, 0, (size_t)2 * ND * sizeof(float), stream);
    k_gemm_re<<<ggrid, 256, 0, stream>>>(Ahi, Alo, Whi, Wlo, be, idxs, scs, pre, ctl, -1);
    k_gemm_im<<<ggrid, 256, 0, stream>>>(zimB, Whi, idxs, scs, pim, ctl, -1);
    k_final_zupd<<<ND / 256, 256, 0, stream>>>(zre, zimB, x_real, x_imag, rc, rs, pre, pim);
    k_write_out<<<ND / 256, 256, 0, stream>>>(zre, zimB, (float*)d_out, ctl);
}

// Round 3
// 2470.468 us; speedup vs baseline: 2.2829x; 1.0799x over previous
//
#include <hip/hip_runtime.h>
#include <math.h>

#define ND    8388608
#define NTOK  8192
#define DIM   1024
#define NEXP  8
#define CAP   1024
#define TSEQ  2048

typedef short bf16x8 __attribute__((ext_vector_type(8)));
typedef unsigned short u16x8 __attribute__((ext_vector_type(8)));
typedef float f32x4 __attribute__((ext_vector_type(4)));

#define AS1 __attribute__((address_space(1)))
#define AS3 __attribute__((address_space(3)))

__device__ __forceinline__ void gload_lds16(const void* g, void* l) {
    __builtin_amdgcn_global_load_lds((const AS1 unsigned int*)g,
                                     (AS3 unsigned int*)l, 16, 0, 0);
}

__device__ __forceinline__ unsigned short f2bf(float x) {
    union { float f; unsigned u; } v; v.f = x;
    unsigned r = v.u + 0x7FFFu + ((v.u >> 16) & 1u);
    return (unsigned short)(r >> 16);
}
__device__ __forceinline__ float bf2f(unsigned short b) {
    union { unsigned u; float f; } v; v.u = ((unsigned)b) << 16; return v.f;
}

// ---------------- init ----------------
__global__ void k_init_small(const float* __restrict__ phase, const int* __restrict__ Lptr,
                             float* __restrict__ rc, float* __restrict__ rs,
                             int* __restrict__ ctl) {
    int d = blockIdx.x * blockDim.x + threadIdx.x;
    if (d < DIM) { rc[d] = cosf(phase[d]); rs[d] = sinf(phase[d]); }
    if (d == 0) {
        ctl[0] = 0; ctl[1] = 0;
        int L = Lptr[0]; int mi = L - 1; if (mi < 1) mi = 1;
        ctl[2] = mi;
    }
}

__global__ void k_init_big(const float* __restrict__ xr, const float* __restrict__ xi,
                           float* __restrict__ zre, unsigned short* __restrict__ zimB) {
    int i = blockIdx.x * blockDim.x + threadIdx.x;
    if (i >= ND) return;
    zre[i] = xr[i];
    zimB[i] = f2bf(xi[i]);
}

// ---------------- one-time: We -> weT hi/lo bf16, [e][h][d], slot-swizzled by h&7 ----------------
__global__ __launch_bounds__(256) void k_wconv(const float* __restrict__ We,
                                               unsigned short* __restrict__ Whi,
                                               unsigned short* __restrict__ Wlo) {
    __shared__ float lds[64][65];
    int e = blockIdx.z, h0 = blockIdx.x * 64, d0 = blockIdx.y * 64;
    int tid = threadIdx.x;
    #pragma unroll
    for (int q = 0; q < 16; ++q) {
        int idx = q * 256 + tid;
        int i = idx >> 6, j = idx & 63;
        lds[i][j] = We[(size_t)e * 1048576 + (size_t)(d0 + i) * 1024 + h0 + j];
    }
    __syncthreads();
    #pragma unroll
    for (int q = 0; q < 2; ++q) {
        int sid = q * 256 + tid;
        int j = sid >> 3, sp = sid & 7;
        int h = h0 + j;
        int slog = sp ^ (h & 7);
        u16x8 hi, lo;
        #pragma unroll
        for (int u = 0; u < 8; ++u) {
            float x = lds[slog * 8 + u][j];
            unsigned short hb = f2bf(x);
            hi[u] = hb;
            lo[u] = f2bf(x - bf2f(hb));
        }
        size_t o = (((size_t)(e << 10) + h) << 10) + d0 + sp * 8;
        *(u16x8*)(Whi + o) = hi;
        *(u16x8*)(Wlo + o) = lo;
    }
}

// ---------------- gating: logits + softmax ----------------
__global__ __launch_bounds__(256) void k_gate_softmax(
    const float* __restrict__ zre, const float* __restrict__ Wg, const float* __restrict__ bg,
    float* __restrict__ S, float* __restrict__ sumbuf,
    const int* __restrict__ ctl, int iter) {
    if (iter >= 0 && (ctl[0] || iter >= ctl[2])) return;
    if (blockIdx.x == 0 && threadIdx.x == 0) *sumbuf = 0.0f;
    int wave = threadIdx.x >> 6;
    int lane = threadIdx.x & 63;
    int n = blockIdx.x * 4 + wave;
    float acc[NEXP] = {0,0,0,0,0,0,0,0};
    const float* zr = zre + (size_t)n * DIM;
    for (int d = lane; d < DIM; d += 64) {
        float zv = zr[d];
        const float4 w0 = *(const float4*)(Wg + d * 8);
        const float4 w1 = *(const float4*)(Wg + d * 8 + 4);
        acc[0] += zv * w0.x; acc[1] += zv * w0.y; acc[2] += zv * w0.z; acc[3] += zv * w0.w;
        acc[4] += zv * w1.x; acc[5] += zv * w1.y; acc[6] += zv * w1.z; acc[7] += zv * w1.w;
    }
    #pragma unroll
    for (int off = 32; off > 0; off >>= 1)
        #pragma unroll
        for (int e = 0; e < NEXP; ++e) acc[e] += __shfl_xor(acc[e], off);
    if (lane == 0) {
        float m = -1e30f;
        #pragma unroll
        for (int e = 0; e < NEXP; ++e) { acc[e] += bg[e]; m = fmaxf(m, acc[e]); }
        float ssum = 0.0f;
        #pragma unroll
        for (int e = 0; e < NEXP; ++e) { acc[e] = expf(acc[e] - m); ssum += acc[e]; }
        float inv = 1.0f / ssum;
        #pragma unroll
        for (int e = 0; e < NEXP; ++e) S[n * 8 + e] = acc[e] * inv;
    }
}

// ---------------- top-k by rank counting ----------------
// key = (score_bits<<32) | ~token (strict total order). rank = #{j: key_j > key_i}.
// Selected tokens have ranks 0..CAP-1 exactly == jax top_k order (ties -> lower idx).
__global__ __launch_bounds__(256) void k_select(
    const float* __restrict__ S, int* __restrict__ idxs, float* __restrict__ scs,
    const int* __restrict__ ctl, int iter) {
    if (iter >= 0 && (ctl[0] || iter >= ctl[2])) return;
    __shared__ unsigned long long keys[NTOK];   // 64 KiB
    const int e = blockIdx.y;
    const int tid = threadIdx.x;
    for (int j = tid; j < NTOK; j += 256) {
        unsigned sb = __float_as_uint(S[j * 8 + e]);   // softmax > 0: bits order-preserving
        keys[j] = ((unsigned long long)sb << 32) | (unsigned)(0xFFFFFFFFu - (unsigned)j);
    }
    __syncthreads();
    const int n = blockIdx.x * 256 + tid;
    const unsigned long long mykey = keys[n];
    int cnt = 0;
    for (int j = 0; j < NTOK; j += 8) {
        unsigned long long k0 = keys[j + 0], k1 = keys[j + 1];
        unsigned long long k2 = keys[j + 2], k3 = keys[j + 3];
        unsigned long long k4 = keys[j + 4], k5 = keys[j + 5];
        unsigned long long k6 = keys[j + 6], k7 = keys[j + 7];
        cnt += (int)(k0 > mykey) + (int)(k1 > mykey) + (int)(k2 > mykey) + (int)(k3 > mykey)
             + (int)(k4 > mykey) + (int)(k5 > mykey) + (int)(k6 > mykey) + (int)(k7 > mykey);
    }
    if (cnt < CAP) {
        idxs[e * CAP + cnt] = n;
        scs[e * CAP + cnt]  = __uint_as_float((unsigned)(mykey >> 32));
    }
}

// ---------------- gather selected z.re rows -> Ahi/Alo bf16, slot-swizzled by row&7 ----------------
__global__ __launch_bounds__(256) void k_gather_convert(
    const float* __restrict__ zre, const int* __restrict__ idxs,
    unsigned short* __restrict__ Ahi, unsigned short* __restrict__ Alo,
    const int* __restrict__ ctl, int iter) {
    if (iter >= 0 && (ctl[0] || iter >= ctl[2])) return;
    int g = blockIdx.x * 256 + threadIdx.x;       // 0 .. 8192*128-1
    int r = g >> 7;
    int sl = g & 127;
    int c = sl >> 3, sp = sl & 7;
    int slog = sp ^ (r & 7);
    int n = idxs[r];
    const float* src = zre + ((size_t)n << 10) + c * 64 + slog * 8;
    u16x8 hi, lo;
    #pragma unroll
    for (int u = 0; u < 8; ++u) {
        float x = src[u];
        unsigned short hb = f2bf(x);
        hi[u] = hb;
        lo[u] = f2bf(x - bf2f(hb));
    }
    size_t o = ((size_t)r << 10) + c * 64 + sp * 8;
    *(u16x8*)(Ahi + o) = hi;
    *(u16x8*)(Alo + o) = lo;
}

// ---------------- real GEMM: 3-pass hi/lo MFMA + scatter ----------------
__global__ __launch_bounds__(256, 2) void k_gemm_re(
    const unsigned short* __restrict__ Ahi, const unsigned short* __restrict__ Alo,
    const unsigned short* __restrict__ Whi, const unsigned short* __restrict__ Wlo,
    const float* __restrict__ be, const int* __restrict__ idxs, const float* __restrict__ scs,
    float* __restrict__ pre, const int* __restrict__ ctl, int iter) {
    if (iter >= 0 && (ctl[0] || iter >= ctl[2])) return;
    __shared__ unsigned short smem[32768];   // 64KB: Ahi|Alo|Whi|Wlo tiles, [128][64] each
    const int e = blockIdx.z, bx = blockIdx.x, by = blockIdx.y;
    const int tid = threadIdx.x;
    const int wid = tid >> 6, lane = tid & 63;
    const int wm = wid >> 1, wn = wid & 1;

    const unsigned short* srcbase;
    int rowbase;
    if (wid == 0)      { srcbase = Ahi; rowbase = (e << 10) + by * 128; }
    else if (wid == 1) { srcbase = Alo; rowbase = (e << 10) + by * 128; }
    else if (wid == 2) { srcbase = Whi; rowbase = (e << 10) + bx * 128; }
    else               { srcbase = Wlo; rowbase = (e << 10) + bx * 128; }
    const unsigned short* gsrc = srcbase + (((size_t)(rowbase + (lane >> 3))) << 10) + ((lane & 7) << 3);
    unsigned short* ldst = smem + (wid << 13);

    f32x4 acc[4][4];
    #pragma unroll
    for (int a = 0; a < 4; ++a)
        #pragma unroll
        for (int b = 0; b < 4; ++b) acc[a][b] = (f32x4){0.f, 0.f, 0.f, 0.f};

    for (int kt = 0; kt < DIM; kt += 64) {
        __syncthreads();
        #pragma unroll
        for (int i = 0; i < 16; ++i)
            gload_lds16(gsrc + kt + ((size_t)i << 13), ldst + i * 512);
        __syncthreads();
        #pragma unroll
        for (int ks = 0; ks < 2; ++ks) {
            const int slog = (ks << 2) + (lane >> 4);
            const int swz = (slog ^ (lane & 7)) << 3;
            bf16x8 ah[4], al[4], bh[4], bl[4];
            #pragma unroll
            for (int mi = 0; mi < 4; ++mi) {
                int off = ((wm * 64 + mi * 16 + (lane & 15)) << 6) + swz;
                ah[mi] = *(const bf16x8*)&smem[off];
                al[mi] = *(const bf16x8*)&smem[8192 + off];
            }
            #pragma unroll
            for (int ni = 0; ni < 4; ++ni) {
                int off = ((wn * 64 + ni * 16 + (lane & 15)) << 6) + swz;
                bh[ni] = *(const bf16x8*)&smem[16384 + off];
                bl[ni] = *(const bf16x8*)&smem[24576 + off];
            }
            #pragma unroll
            for (int mi = 0; mi < 4; ++mi)
                #pragma unroll
                for (int ni = 0; ni < 4; ++ni) {
                    acc[mi][ni] = __builtin_amdgcn_mfma_f32_16x16x32_bf16(ah[mi], bh[ni], acc[mi][ni], 0, 0, 0);
                    acc[mi][ni] = __builtin_amdgcn_mfma_f32_16x16x32_bf16(ah[mi], bl[ni], acc[mi][ni], 0, 0, 0);
                    acc[mi][ni] = __builtin_amdgcn_mfma_f32_16x16x32_bf16(al[mi], bh[ni], acc[mi][ni], 0, 0, 0);
                }
        }
    }
    const int colbase = bx * 128 + wn * 64 + (lane & 15);
    float bev[4];
    #pragma unroll
    for (int ni = 0; ni < 4; ++ni) bev[ni] = be[(e << 10) + colbase + ni * 16];
    const int rowg = (e << 10) + by * 128 + wm * 64 + ((lane >> 4) << 2);
    #pragma unroll
    for (int mi = 0; mi < 4; ++mi) {
        #pragma unroll
        for (int rg = 0; rg < 4; ++rg) {
            int k = rowg + mi * 16 + rg;
            int tok = idxs[k];
            float s = scs[k];
            float* ob = pre + ((size_t)tok << 10);
            #pragma unroll
            for (int ni = 0; ni < 4; ++ni)
                atomicAdd(ob + colbase + ni * 16, s * (acc[mi][ni][rg] + bev[ni]));
        }
    }
}

// ---------------- imag GEMM: 1-pass bf16 MFMA + scatter ----------------
__global__ __launch_bounds__(256, 2) void k_gemm_im(
    const unsigned short* __restrict__ zimB, const unsigned short* __restrict__ Whi,
    const int* __restrict__ idxs, const float* __restrict__ scs,
    float* __restrict__ pim, const int* __restrict__ ctl, int iter) {
    if (iter >= 0 && (ctl[0] || iter >= ctl[2])) return;
    __shared__ unsigned short smem[16384];   // Aim[8192] | Bhi[8192]
    __shared__ int   tokL[128];
    __shared__ float scL[128];
    const int e = blockIdx.z, bx = blockIdx.x, by = blockIdx.y;
    const int tid = threadIdx.x;
    const int wid = tid >> 6, lane = tid & 63;
    const int wm = wid >> 1, wn = wid & 1;
    if (tid < 128) {
        tokL[tid] = idxs[(e << 10) + by * 128 + tid];
        scL[tid]  = scs[(e << 10) + by * 128 + tid];
    }
    __syncthreads();

    f32x4 acc[4][4];
    #pragma unroll
    for (int a = 0; a < 4; ++a)
        #pragma unroll
        for (int b = 0; b < 4; ++b) acc[a][b] = (f32x4){0.f, 0.f, 0.f, 0.f};

    const int rl = lane >> 3;          // 0..7
    const int ch = lane & 7;
    const int swzst = (ch ^ rl) << 3;  // source-folded swizzle for A staging
    const unsigned short* wsrc = Whi + (((size_t)((e << 10) + bx * 128 + rl)) << 10) + (ch << 3);

    for (int kt = 0; kt < DIM; kt += 64) {
        __syncthreads();
        if (wid < 2) {
            u16x8 tmp[8];
            #pragma unroll
            for (int q = 0; q < 8; ++q) {
                int r = (wid << 6) + (q << 3) + rl;
                int tok = tokL[r];
                tmp[q] = *(const u16x8*)(zimB + ((size_t)tok << 10) + kt + swzst);
            }
            #pragma unroll
            for (int q = 0; q < 8; ++q) {
                int r = (wid << 6) + (q << 3) + rl;
                *(u16x8*)&smem[(r << 6) + (ch << 3)] = tmp[q];
            }
        } else {
            #pragma unroll
            for (int q = 0; q < 8; ++q) {
                int i = ((wid - 2) << 3) + q;
                gload_lds16(wsrc + kt + ((size_t)i << 13), smem + 8192 + i * 512);
            }
        }
        __syncthreads();
        #pragma unroll
        for (int ks = 0; ks < 2; ++ks) {
            const int slog = (ks << 2) + (lane >> 4);
            const int swz = (slog ^ (lane & 7)) << 3;
            bf16x8 am[4], bh[4];
            #pragma unroll
            for (int mi = 0; mi < 4; ++mi) {
                int off = ((wm * 64 + mi * 16 + (lane & 15)) << 6) + swz;
                am[mi] = *(const bf16x8*)&smem[off];
            }
            #pragma unroll
            for (int ni = 0; ni < 4; ++ni) {
                int off = ((wn * 64 + ni * 16 + (lane & 15)) << 6) + swz;
                bh[ni] = *(const bf16x8*)&smem[8192 + off];
            }
            #pragma unroll
            for (int mi = 0; mi < 4; ++mi)
                #pragma unroll
                for (int ni = 0; ni < 4; ++ni)
                    acc[mi][ni] = __builtin_amdgcn_mfma_f32_16x16x32_bf16(am[mi], bh[ni], acc[mi][ni], 0, 0, 0);
        }
    }
    const int colbase = bx * 128 + wn * 64 + (lane & 15);
    #pragma unroll
    for (int mi = 0; mi < 4; ++mi) {
        #pragma unroll
        for (int rg = 0; rg < 4; ++rg) {
            int rloc = wm * 64 + mi * 16 + ((lane >> 4) << 2) + rg;
            int tok = tokL[rloc];
            float s = scL[rloc];
            float* ob = pim + ((size_t)tok << 10);
            #pragma unroll
            for (int ni = 0; ni < 4; ++ni)
                atomicAdd(ob + colbase + ni * 16, s * acc[mi][ni][rg]);
        }
    }
}

// ---------------- residual, z update, |r| reduction (target recomputed from x) ----------------
__global__ __launch_bounds__(256) void k_resid_update(
    float* __restrict__ zre, unsigned short* __restrict__ zimB,
    const float* __restrict__ xr, const float* __restrict__ xi,
    const float* __restrict__ rc, const float* __restrict__ rs,
    const float* __restrict__ pre, const float* __restrict__ pim,
    float lr, float* __restrict__ sumbuf, const int* __restrict__ ctl, int iter) {
    if (ctl[0] || iter >= ctl[2]) return;
    __shared__ float red[256];
    float local = 0.0f;
    int stride = gridDim.x * blockDim.x;
    for (int i = blockIdx.x * blockDim.x + threadIdx.x; i < ND; i += stride) {
        int d = i & (DIM - 1);
        int t = (i >> 10) & (TSEQ - 1);
        float trv, tiv;
        if (t == 0) { trv = xr[i]; tiv = xi[i]; }
        else {
            float ar = xr[i - DIM], ai = xi[i - DIM];
            float c = rc[d], s = rs[d];
            trv = ar * c - ai * s;
            tiv = ar * s + ai * c;
        }
        float rr = trv - pre[i];
        float ri = tiv - pim[i];
        zre[i] += lr * rr;
        zimB[i] = f2bf(bf2f(zimB[i]) + lr * ri);
        local += sqrtf(rr * rr + ri * ri);
    }
    red[threadIdx.x] = local;
    __syncthreads();
    for (int s = 128; s > 0; s >>= 1) {
        if (threadIdx.x < s) red[threadIdx.x] += red[threadIdx.x + s];
        __syncthreads();
    }
    if (threadIdx.x == 0) atomicAdd(sumbuf, red[0]);
}

__global__ void k_finalize(const float* __restrict__ sumbuf, int* __restrict__ ctl, int iter) {
    if (ctl[0] || iter >= ctl[2]) return;
    ctl[1] = iter + 1;
    float mean = *sumbuf * (1.0f / (float)ND);
    if (mean < 0.001f) ctl[0] = 1;
}

// ---------------- final: z += 0.5*(tgt - pred); write stacked output ----------------
__global__ void k_final_zupd(float* __restrict__ zre, unsigned short* __restrict__ zimB,
                             const float* __restrict__ xr, const float* __restrict__ xi,
                             const float* __restrict__ rc, const float* __restrict__ rs,
                             const float* __restrict__ pre, const float* __restrict__ pim) {
    int i = blockIdx.x * blockDim.x + threadIdx.x;
    if (i >= ND) return;
    int d = i & (DIM - 1);
    int t = (i >> 10) & (TSEQ - 1);
    float trv, tiv;
    if (t == 0) { trv = xr[i]; tiv = xi[i]; }
    else {
        float ar = xr[i - DIM], ai = xi[i - DIM];
        float c = rc[d], s = rs[d];
        trv = ar * c - ai * s;
        tiv = ar * s + ai * c;
    }
    zre[i] += 0.5f * (trv - pre[i]);
    zimB[i] = f2bf(bf2f(zimB[i]) + 0.5f * (tiv - pim[i]));
}

__global__ void k_write_out(const float* __restrict__ zre, const unsigned short* __restrict__ zimB,
                            float* __restrict__ out, const int* __restrict__ ctl) {
    int i = blockIdx.x * blockDim.x + threadIdx.x;
    if (i >= ND) return;
    out[2 * i]     = zre[i];
    out[2 * i + 1] = bf2f(zimB[i]);
    if (i == 0) out[(size_t)2 * ND] = (float)ctl[1];
}

// ---------------- host ----------------
extern "C" void kernel_launch(void* const* d_in, const int* in_sizes, int n_in,
                              void* d_out, int out_size, void* d_ws, size_t ws_size,
                              hipStream_t stream) {
    (void)in_sizes; (void)n_in; (void)out_size; (void)ws_size;
    const float* x_real = (const float*)d_in[0];
    const float* x_imag = (const float*)d_in[1];
    const float* phase  = (const float*)d_in[2];
    const float* Wg     = (const float*)d_in[3];
    const float* bg     = (const float*)d_in[4];
    const float* We     = (const float*)d_in[5];
    const float* be     = (const float*)d_in[6];
    const int*   Lptr   = (const int*)d_in[7];

    char* wsb = (char*)d_ws;
    float*          zre  = (float*)wsb;                                  // 32MB
    unsigned short* zimB = (unsigned short*)(wsb + 33554432);            // 16MB
    unsigned short* Ahi  = (unsigned short*)(wsb + 50331648);            // 16MB
    unsigned short* Alo  = (unsigned short*)(wsb + 67108864);            // 16MB
    unsigned short* Whi  = (unsigned short*)(wsb + 83886080);            // 16MB
    unsigned short* Wlo  = (unsigned short*)(wsb + 100663296);           // 16MB
    float* S      = (float*)(wsb + 117440512);
    float* scs    = (float*)(wsb + 117702656);
    int*   idxs   = (int*)  (wsb + 117735424);
    float* rc     = (float*)(wsb + 117768192);
    float* rs     = (float*)(wsb + 117772288);
    float* sumbuf = (float*)(wsb + 117776384);
    int*   ctl    = (int*)  (wsb + 117776388);

    float* pre = (float*)d_out;
    float* pim = pre + (size_t)ND;

    k_init_small<<<4, 256, 0, stream>>>(phase, Lptr, rc, rs, ctl);
    k_init_big<<<ND / 256, 256, 0, stream>>>(x_real, x_imag, zre, zimB);
    k_wconv<<<dim3(16, 16, 8), 256, 0, stream>>>(We, Whi, Wlo);

    dim3 ggrid(8, 8, 8);
    dim3 sgrid(NTOK / 256, NEXP);
    float lr = 0.5f;
    for (int it = 0; it < 7; ++it) {
        k_gate_softmax<<<NTOK / 4, 256, 0, stream>>>(zre, Wg, bg, S, sumbuf, ctl, it);
        k_select<<<sgrid, 256, 0, stream>>>(S, idxs, scs, ctl, it);
        k_gather_convert<<<4096, 256, 0, stream>>>(zre, idxs, Ahi, Alo, ctl, it);
        hipMemsetAsync(d_out, 0, (size_t)2 * ND * sizeof(float), stream);
        k_gemm_re<<<ggrid, 256, 0, stream>>>(Ahi, Alo, Whi, Wlo, be, idxs, scs, pre, ctl, it);
        k_gemm_im<<<ggrid, 256, 0, stream>>>(zimB, Whi, idxs, scs, pim, ctl, it);
        k_resid_update<<<2048, 256, 0, stream>>>(zre, zimB, x_real, x_imag, rc, rs, pre, pim, lr, sumbuf, ctl, it);
        k_finalize<<<1, 1, 0, stream>>>(sumbuf, ctl, it);
        lr *= 0.85f;
    }

    k_gate_softmax<<<NTOK / 4, 256, 0, stream>>>(zre, Wg, bg, S, sumbuf, ctl, -1);
    k_select<<<sgrid, 256, 0, stream>>>(S, idxs, scs, ctl, -1);
    k_gather_convert<<<4096, 256, 0, stream>>>(zre, idxs, Ahi, Alo, ctl, -1);
    hipMemsetAsync(d_out, 0, (size_t)2 * ND * sizeof(float), stream);
    k_gemm_re<<<ggrid, 256, 0, stream>>>(Ahi, Alo, Whi, Wlo, be, idxs, scs, pre, ctl, -1);
    k_gemm_im<<<ggrid, 256, 0, stream>>>(zimB, Whi, idxs, scs, pim, ctl, -1);
    k_final_zupd<<<ND / 256, 256, 0, stream>>>(zre, zimB, x_real, x_imag, rc, rs, pre, pim);
    k_write_out<<<ND / 256, 256, 0, stream>>>(zre, zimB, (float*)d_out, ctl);
}